// Round 10
// baseline (103.627 us; speedup 1.0000x reference)
//
#include <hip/hip_runtime.h>
#include <hip/hip_bf16.h>

#define N_POINTS 262144
#define N_NODES  8192
#define IN_C     256
#define HID      512
#define OUT_C    256
#define NB       16
#define MAXN     512
#define EPSV     1e-5f
#define NPB      32   // nodes per fused block

typedef __attribute__((ext_vector_type(8))) short short8;   // 8 bf16 = 4 VGPR
typedef __attribute__((ext_vector_type(4))) float f32x4;    // MFMA acc
typedef __attribute__((ext_vector_type(4))) float f4v;
#define MFMA16(a, b, c) __builtin_amdgcn_mfma_f32_16x16x32_bf16((a), (b), (c), 0, 0, 0)

// Fragment layout (gfx950 mfma_f32_16x16x32_bf16, m89-verified):
//   A[m][k]: m = lane&15, k = (lane>>4)*8 + j
//   B[k][n]: n = lane&15, k = (lane>>4)*8 + j
//   D[m][n]: n = lane&15, m = (lane>>4)*4 + reg

// ---------------------------------------------------------------------------
// Kernel 0 (prelude): blockIdx.x < 1024 -> node range boundaries from sorted
// fpb (thread per point); else pack W fp32 -> fragment-packed bf16 so each
// MFMA B-fragment load is one 1 KB coalesced read.
// ---------------------------------------------------------------------------
__global__ __launch_bounds__(256) void prelude_k(
    const int* __restrict__ fpb, int* __restrict__ starts,
    const float* __restrict__ W1q, const float* __restrict__ W1k,
    const float* __restrict__ W2q, const float* __restrict__ W2k,
    __hip_bfloat16* __restrict__ P1q, __hip_bfloat16* __restrict__ P1k,
    __hip_bfloat16* __restrict__ P2q, __hip_bfloat16* __restrict__ P2k)
{
  if (blockIdx.x < 1024) {
    const int i = blockIdx.x * 256 + threadIdx.x;
    const int cur = fpb[i];
    const int prev = (i == 0) ? -1 : fpb[i - 1];
    for (int n = prev + 1; n <= cur; ++n) starts[n] = i;   // usually 0 or 1 iters
    if (i == N_POINTS - 1)
      for (int n = cur + 1; n <= N_NODES; ++n) starts[n] = N_POINTS;
    return;
  }
  const int bid = blockIdx.x - 1024;       // 0..255
  const int sel = bid >> 6;                // which weight
  const float* W; __hip_bfloat16* P; int N;
  switch (sel) {
    case 0:  W = W1q; P = P1q; N = HID;   break;
    case 1:  W = W1k; P = P1k; N = HID;   break;
    case 2:  W = W2q; P = P2q; N = OUT_C; break;
    default: W = W2k; P = P2k; N = OUT_C; break;
  }
  const int idx = (bid & 63) * 256 + threadIdx.x;  // (ks, nf, lane), 16384 total
  const int NF = N >> 4;
  const int lane = idx & 63;
  const int nf = (idx >> 6) % NF;
  const int ks = idx / (64 * NF);
  const int k0 = ks * 32 + (lane >> 4) * 8;
  const int n  = nf * 16 + (lane & 15);
  __hip_bfloat16 tmp[8];
  #pragma unroll
  for (int j = 0; j < 8; ++j) tmp[j] = __float2bfloat16(W[(size_t)(k0 + j) * N + n]);
  *(uint4*)(P + (size_t)idx * 8) = *(uint4*)tmp;
}

// ---------------------------------------------------------------------------
// Row accumulator: 4-deep pipelined float4 row sweep (R6-proven pattern).
// ---------------------------------------------------------------------------
__device__ __forceinline__ void accum_rows(
    const float* __restrict__ x, int lo, int hi, int l,
    f4v& a0, f4v& a1, f4v& a2, f4v& a3)
{
  int r = lo;
  for (; r + 4 <= hi; r += 4) {
    f4v v0 = *(const f4v*)(x + (size_t)(r + 0) * IN_C + l * 4);
    f4v v1 = *(const f4v*)(x + (size_t)(r + 1) * IN_C + l * 4);
    f4v v2 = *(const f4v*)(x + (size_t)(r + 2) * IN_C + l * 4);
    f4v v3 = *(const f4v*)(x + (size_t)(r + 3) * IN_C + l * 4);
    a0 += v0; a1 += v1; a2 += v2; a3 += v3;
  }
  for (; r < hi; ++r)
    a0 += *(const f4v*)(x + (size_t)r * IN_C + l * 4);
}

// ---------------------------------------------------------------------------
// Kernel 1: FUSED scatter-mean + both-head-parallel MLP (R7 MLP structure,
// R6 stream occupancy, LDS-aliased).
// 256 blocks x 512 thr (8 waves), 32 nodes/block. LDS 68.6 KB -> 2 blocks/CU
// = 16 stream-waves/CU. __launch_bounds__(512,4) caps VGPR at 128.
// Stream: wave w owns nodes 4w..4w+3, 4-deep row pipeline -> means to As.
// MLP: wave = (head h = w>>2, col-quarter c = w&3); GEMM1 m_rep=2 over
// [32][128c..]; LN via 16-lane shfl + 4-wave LDS combine; Hs[h] (Hs1 ALIASES
// As -- As is dead after the post-GEMM1 barrier); GEMM2 [32][64c..]; store.
// 3 barriers. Weight traffic 1 MB/block -> 256 MB L2 total (half of R6).
// ---------------------------------------------------------------------------
__global__ __launch_bounds__(512, 4) void fused_mlp_k(
    const float* __restrict__ x, const int* __restrict__ starts,
    const __hip_bfloat16* __restrict__ P1q, const __hip_bfloat16* __restrict__ P2q,
    const float* __restrict__ b1q, const float* __restrict__ g1q,
    const float* __restrict__ be1q, const float* __restrict__ b2q,
    const __hip_bfloat16* __restrict__ P1k, const __hip_bfloat16* __restrict__ P2k,
    const float* __restrict__ b1k, const float* __restrict__ g1k,
    const float* __restrict__ be1k, const float* __restrict__ b2k,
    __hip_bfloat16* __restrict__ qo, __hip_bfloat16* __restrict__ ko)
{
  const int n0 = blockIdx.x * NPB;
  const int t = threadIdx.x;
  const int w = t >> 6, l = t & 63, lg = l >> 4, lm = l & 15;
  const int h = w >> 2;      // head: 0=q 1=k
  const int c = w & 3;       // column quarter

  const __hip_bfloat16* P1 = h ? P1k : P1q;
  const __hip_bfloat16* P2 = h ? P2k : P2q;
  const float* b1  = h ? b1k  : b1q;
  const float* g1  = h ? g1k  : g1q;
  const float* be1 = h ? be1k : be1q;
  const float* b2  = h ? b2k  : b2q;
  __hip_bfloat16* out = h ? ko : qo;

  __shared__ __hip_bfloat16 HsBuf[2 * NPB * 520];   // 66.6 KB
  __shared__ float lnp[8][NPB][2];                  //  2 KB
  __hip_bfloat16* Hs0 = HsBuf;                // head q h-buffer
  __hip_bfloat16* Hs1 = HsBuf + NPB * 520;    // head k h-buffer
  __hip_bfloat16* As  = Hs1;                  // A-tile ALIASES Hs1 (dead after GEMM1)
  __hip_bfloat16* Hsh = h ? Hs1 : Hs0;

  // ---- Phase 1: stream x rows, per-wave node means -> As ----
  #pragma unroll
  for (int i = 0; i < 4; ++i) {
    const int nl = w * 4 + i;
    const int node = n0 + nl;
    const int s_ = starts[node], e_ = starts[node + 1];
    f4v a0 = (f4v)0.f, a1 = (f4v)0.f, a2 = (f4v)0.f, a3 = (f4v)0.f;
    accum_rows(x, s_, e_, l, a0, a1, a2, a3);
    a0 += a1 + a2 + a3;
    const int cnt = e_ - s_;
    const float inv = cnt > 0 ? 1.0f / (float)cnt : 0.0f;
    __hip_bfloat16 o[4];
    o[0] = __float2bfloat16(a0.x * inv);
    o[1] = __float2bfloat16(a0.y * inv);
    o[2] = __float2bfloat16(a0.z * inv);
    o[3] = __float2bfloat16(a0.w * inv);
    *(uint2*)(As + nl * 264 + l * 4) = *(uint2*)o;
  }
  __syncthreads();

  // ---- Phase 2: GEMM1: C1[32][128c..] = A[32][256] x W1[256][128c..] ----
  f32x4 acc1[2][8];
  #pragma unroll
  for (int mi = 0; mi < 2; ++mi)
    #pragma unroll
    for (int nj = 0; nj < 8; ++nj)
      #pragma unroll
      for (int r = 0; r < 4; ++r) acc1[mi][nj][r] = 0.f;

  for (int ks = 0; ks < 8; ++ks) {
    short8 a0 = *(const short8*)(As + lm * 264 + ks * 32 + lg * 8);
    short8 a1 = *(const short8*)(As + (16 + lm) * 264 + ks * 32 + lg * 8);
    const __hip_bfloat16* bp = P1 + ((size_t)(ks * 32 + c * 8) * 64 + l) * 8;
    #pragma unroll
    for (int nj = 0; nj < 8; ++nj) {
      short8 b = *(const short8*)(bp + (size_t)nj * 512);
      acc1[0][nj] = MFMA16(a0, b, acc1[0][nj]);
      acc1[1][nj] = MFMA16(a1, b, acc1[1][nj]);
    }
  }

  float b1v[8], g1v[8], e1v[8];
  #pragma unroll
  for (int nj = 0; nj < 8; ++nj) {
    const int col = c * 128 + nj * 16 + lm;
    b1v[nj] = b1[col]; g1v[nj] = g1[col]; e1v[nj] = be1[col];
  }
  #pragma unroll
  for (int mi = 0; mi < 2; ++mi)
    #pragma unroll
    for (int nj = 0; nj < 8; ++nj)
      #pragma unroll
      for (int r = 0; r < 4; ++r) acc1[mi][nj][r] += b1v[nj];

  // LN partials over this wave's 128 cols (16-lane shfl reduce)
  #pragma unroll
  for (int mi = 0; mi < 2; ++mi)
    #pragma unroll
    for (int r = 0; r < 4; ++r) {
      float s = 0.f, q = 0.f;
      #pragma unroll
      for (int nj = 0; nj < 8; ++nj) {
        const float v = acc1[mi][nj][r];
        s += v; q += v * v;
      }
      #pragma unroll
      for (int off = 1; off < 16; off <<= 1) {
        s += __shfl_xor(s, off);
        q += __shfl_xor(q, off);
      }
      if (lm == 0) {
        const int row = mi * 16 + lg * 4 + r;
        lnp[w][row][0] = s;
        lnp[w][row][1] = q;
      }
    }
  __syncthreads();   // As dead from here; Hs1 may be written

  // ---- Phase 3: finish LN (combine this head's 4 waves), relu, h -> Hs[h] ----
  #pragma unroll
  for (int mi = 0; mi < 2; ++mi)
    #pragma unroll
    for (int r = 0; r < 4; ++r) {
      const int row = mi * 16 + lg * 4 + r;
      float S = 0.f, Q = 0.f;
      #pragma unroll
      for (int w2 = 0; w2 < 4; ++w2) {
        S += lnp[h * 4 + w2][row][0];
        Q += lnp[h * 4 + w2][row][1];
      }
      const float mu = S * (1.0f / HID);
      const float rs = rsqrtf(Q * (1.0f / HID) - mu * mu + EPSV);
      #pragma unroll
      for (int nj = 0; nj < 8; ++nj) {
        const float y = (acc1[mi][nj][r] - mu) * rs * g1v[nj] + e1v[nj];
        Hsh[row * 520 + c * 128 + nj * 16 + lm] = __float2bfloat16(fmaxf(y, 0.f));
      }
    }
  __syncthreads();

  // ---- Phase 4: GEMM2: C2[32][64c..] = h[32][512] x W2[512][64c..] ----
  f32x4 acc2[2][4];
  #pragma unroll
  for (int mi = 0; mi < 2; ++mi)
    #pragma unroll
    for (int nj = 0; nj < 4; ++nj)
      #pragma unroll
      for (int r = 0; r < 4; ++r) acc2[mi][nj][r] = 0.f;

  for (int ks = 0; ks < 16; ++ks) {
    short8 a0 = *(const short8*)(Hsh + lm * 520 + ks * 32 + lg * 8);
    short8 a1 = *(const short8*)(Hsh + (16 + lm) * 520 + ks * 32 + lg * 8);
    const __hip_bfloat16* bp = P2 + ((size_t)(ks * 16 + c * 4) * 64 + l) * 8;
    #pragma unroll
    for (int nj = 0; nj < 4; ++nj) {
      short8 b = *(const short8*)(bp + (size_t)nj * 512);
      acc2[0][nj] = MFMA16(a0, b, acc2[0][nj]);
      acc2[1][nj] = MFMA16(a1, b, acc2[1][nj]);
    }
  }

  float b2v[4];
  #pragma unroll
  for (int nj = 0; nj < 4; ++nj) b2v[nj] = b2[c * 64 + nj * 16 + lm];
  #pragma unroll
  for (int mi = 0; mi < 2; ++mi)
    #pragma unroll
    for (int nj = 0; nj < 4; ++nj)
      #pragma unroll
      for (int r = 0; r < 4; ++r) {
        const int row = n0 + mi * 16 + lg * 4 + r;
        const int col = c * 64 + nj * 16 + lm;
        out[(size_t)row * OUT_C + col] = __float2bfloat16(acc2[mi][nj][r] + b2v[nj]);
      }
}

// ---------------------------------------------------------------------------
// Kernel 2: out[b] = q_b @ k_b^T, fp32 out. 64x64 tile, 1024 blocks of 4
// waves -> 4 blocks/CU, 4 waves/SIMD. Wave w computes rows [16w,16w+16).
// Operands are contiguous 16 B fragments from L2-resident q/k (no LDS).
// ---------------------------------------------------------------------------
__global__ __launch_bounds__(256, 4) void bmm_k(
    const __hip_bfloat16* __restrict__ q, const __hip_bfloat16* __restrict__ k,
    float* __restrict__ out)
{
  const int b  = blockIdx.z;
  const int n0 = blockIdx.x * 64;
  const int m0 = blockIdx.y * 64;
  const int t = threadIdx.x;
  const int w = t >> 6, l = t & 63, lg = l >> 4, lm = l & 15;

  const __hip_bfloat16* qb = q + ((size_t)b * MAXN + n0 + w * 16) * OUT_C;
  const __hip_bfloat16* kb = k + ((size_t)b * MAXN + m0) * OUT_C;

  f32x4 acc[4];
  #pragma unroll
  for (int nj = 0; nj < 4; ++nj)
    #pragma unroll
    for (int r = 0; r < 4; ++r) acc[nj][r] = 0.f;

  for (int ks = 0; ks < 8; ++ks) {
    short8 a = *(const short8*)(qb + (size_t)lm * OUT_C + ks * 32 + lg * 8);
    #pragma unroll
    for (int nj = 0; nj < 4; ++nj) {
      short8 bb = *(const short8*)(kb + (size_t)(nj * 16 + lm) * OUT_C + ks * 32 + lg * 8);
      acc[nj] = MFMA16(a, bb, acc[nj]);
    }
  }

  #pragma unroll
  for (int nj = 0; nj < 4; ++nj)
    #pragma unroll
    for (int r = 0; r < 4; ++r) {
      const int nrow = n0 + w * 16 + lg * 4 + r;   // q node (output row)
      const int mcol = m0 + nj * 16 + lm;          // k node (output col)
      out[((size_t)b * MAXN + nrow) * MAXN + mcol] = acc[nj][r];
    }
}

// ---------------------------------------------------------------------------
extern "C" void kernel_launch(void* const* d_in, const int* in_sizes, int n_in,
                              void* d_out, int out_size, void* d_ws, size_t ws_size,
                              hipStream_t stream)
{
  const float* x   = (const float*)d_in[0];
  const int*   fpb = (const int*)d_in[1];
  // d_in[2]=g_node_batches (repeat(arange(16),512) -> pad/split is identity
  // reshape), d_in[3]=num_graphs, d_in[4]=max_nodes.
  const float* Wq_w1  = (const float*)d_in[5];
  const float* Wq_b1  = (const float*)d_in[6];
  const float* Wq_g1  = (const float*)d_in[7];
  const float* Wq_be1 = (const float*)d_in[8];
  const float* Wq_w2  = (const float*)d_in[9];
  const float* Wq_b2  = (const float*)d_in[10];
  const float* Wk_w1  = (const float*)d_in[11];
  const float* Wk_b1  = (const float*)d_in[12];
  const float* Wk_g1  = (const float*)d_in[13];
  const float* Wk_be1 = (const float*)d_in[14];
  const float* Wk_w2  = (const float*)d_in[15];
  const float* Wk_b2  = (const float*)d_in[16];

  __hip_bfloat16* ws = (__hip_bfloat16*)d_ws;
  __hip_bfloat16* P1q  = ws;                 // 131072 bf16 each
  __hip_bfloat16* P1k  = P1q + 131072;
  __hip_bfloat16* P2q  = P1k + 131072;
  __hip_bfloat16* P2k  = P2q + 131072;
  __hip_bfloat16* qo   = P2k + 131072;       // 8192*256
  __hip_bfloat16* ko   = qo + 2097152;
  int* starts = (int*)(ko + 2097152);        // 8193 ints
  float* out = (float*)d_out;

  prelude_k<<<1280, 256, 0, stream>>>(fpb, starts,
      Wq_w1, Wk_w1, Wq_w2, Wk_w2, P1q, P1k, P2q, P2k);
  fused_mlp_k<<<N_NODES / NPB, 512, 0, stream>>>(
      x, starts, P1q, P2q, Wq_b1, Wq_g1, Wq_be1, Wq_b2,
      P1k, P2k, Wk_b1, Wk_g1, Wk_be1, Wk_b2, qo, ko);
  bmm_k<<<dim3(8, 8, NB), 256, 0, stream>>>(qo, ko, out);
}

// Round 11
// 87.689 us; speedup vs baseline: 1.1818x; 1.1818x over previous
//
#include <hip/hip_runtime.h>
#include <hip/hip_bf16.h>

#define N_POINTS 262144
#define N_NODES  8192
#define IN_C     256
#define HID      512
#define OUT_C    256
#define NB       16
#define MAXN     512
#define EPSV     1e-5f
#define NPB      32   // nodes per fused block

typedef __attribute__((ext_vector_type(8))) short short8;   // 8 bf16 = 4 VGPR
typedef __attribute__((ext_vector_type(4))) float f32x4;    // MFMA acc
typedef __attribute__((ext_vector_type(4))) float f4v;
#define MFMA16(a, b, c) __builtin_amdgcn_mfma_f32_16x16x32_bf16((a), (b), (c), 0, 0, 0)

// Fragment layout (gfx950 mfma_f32_16x16x32_bf16, m89-verified):
//   A[m][k]: m = lane&15, k = (lane>>4)*8 + j
//   B[k][n]: n = lane&15, k = (lane>>4)*8 + j
//   D[m][n]: n = lane&15, m = (lane>>4)*4 + reg

// ---------------------------------------------------------------------------
// Kernel 0 (prelude): blockIdx.x < 1024 -> node range boundaries from sorted
// fpb (thread per point); else pack W fp32 -> fragment-packed bf16 so each
// MFMA B-fragment load is one 1 KB coalesced read.
// ---------------------------------------------------------------------------
__global__ __launch_bounds__(256) void prelude_k(
    const int* __restrict__ fpb, int* __restrict__ starts,
    const float* __restrict__ W1q, const float* __restrict__ W1k,
    const float* __restrict__ W2q, const float* __restrict__ W2k,
    __hip_bfloat16* __restrict__ P1q, __hip_bfloat16* __restrict__ P1k,
    __hip_bfloat16* __restrict__ P2q, __hip_bfloat16* __restrict__ P2k)
{
  if (blockIdx.x < 1024) {
    const int i = blockIdx.x * 256 + threadIdx.x;
    const int cur = fpb[i];
    const int prev = (i == 0) ? -1 : fpb[i - 1];
    for (int n = prev + 1; n <= cur; ++n) starts[n] = i;   // usually 0 or 1 iters
    if (i == N_POINTS - 1)
      for (int n = cur + 1; n <= N_NODES; ++n) starts[n] = N_POINTS;
    return;
  }
  const int bid = blockIdx.x - 1024;       // 0..255
  const int sel = bid >> 6;                // which weight
  const float* W; __hip_bfloat16* P; int N;
  switch (sel) {
    case 0:  W = W1q; P = P1q; N = HID;   break;
    case 1:  W = W1k; P = P1k; N = HID;   break;
    case 2:  W = W2q; P = P2q; N = OUT_C; break;
    default: W = W2k; P = P2k; N = OUT_C; break;
  }
  const int idx = (bid & 63) * 256 + threadIdx.x;  // (ks, nf, lane), 16384 total
  const int NF = N >> 4;
  const int lane = idx & 63;
  const int nf = (idx >> 6) % NF;
  const int ks = idx / (64 * NF);
  const int k0 = ks * 32 + (lane >> 4) * 8;
  const int n  = nf * 16 + (lane & 15);
  __hip_bfloat16 tmp[8];
  #pragma unroll
  for (int j = 0; j < 8; ++j) tmp[j] = __float2bfloat16(W[(size_t)(k0 + j) * N + n]);
  *(uint4*)(P + (size_t)idx * 8) = *(uint4*)tmp;
}

// ---------------------------------------------------------------------------
// Row accumulator: 4-deep pipelined float4 row sweep (R6-proven pattern).
// ---------------------------------------------------------------------------
__device__ __forceinline__ void accum_rows(
    const float* __restrict__ x, int lo, int hi, int l,
    f4v& a0, f4v& a1, f4v& a2, f4v& a3)
{
  int r = lo;
  for (; r + 4 <= hi; r += 4) {
    f4v v0 = *(const f4v*)(x + (size_t)(r + 0) * IN_C + l * 4);
    f4v v1 = *(const f4v*)(x + (size_t)(r + 1) * IN_C + l * 4);
    f4v v2 = *(const f4v*)(x + (size_t)(r + 2) * IN_C + l * 4);
    f4v v3 = *(const f4v*)(x + (size_t)(r + 3) * IN_C + l * 4);
    a0 += v0; a1 += v1; a2 += v2; a3 += v3;
  }
  for (; r < hi; ++r)
    a0 += *(const f4v*)(x + (size_t)r * IN_C + l * 4);
}

// ---------------------------------------------------------------------------
// Kernel 1: FUSED scatter-mean + both-head-parallel MLP.
// 256 blocks x 1024 thr (16 waves), 32 nodes/block, LDS 85.5 KB -> 1 block/CU
// but 16 STREAM WAVES/CU (== R6's proven stream concurrency).
// __launch_bounds__(1024, 4) -> VGPR cap 128 (explicit: avoids R8's 64-VGPR
// compiler choice). Per-wave register demand ~75 (acc1[2][4]=32, acc2[2][2]=16).
// Stream: wave w owns nodes {2w, 2w+1}, 4-deep row pipeline -> means to As.
// MLP: wave = (head h = w>>3, col-eighth c = w&7); GEMM1 m_rep=2 over
// [32][64c..]; LN via 16-lane shfl + 8-wave LDS combine; relu -> Hs[h];
// GEMM2 [32][32c..]; store. 3 barriers. Weight traffic 1 MB/block -> 256 MB
// L2 total (half of R6's 512 MB).
// ---------------------------------------------------------------------------
__global__ __launch_bounds__(1024, 4) void fused_mlp_k(
    const float* __restrict__ x, const int* __restrict__ starts,
    const __hip_bfloat16* __restrict__ P1q, const __hip_bfloat16* __restrict__ P2q,
    const float* __restrict__ b1q, const float* __restrict__ g1q,
    const float* __restrict__ be1q, const float* __restrict__ b2q,
    const __hip_bfloat16* __restrict__ P1k, const __hip_bfloat16* __restrict__ P2k,
    const float* __restrict__ b1k, const float* __restrict__ g1k,
    const float* __restrict__ be1k, const float* __restrict__ b2k,
    __hip_bfloat16* __restrict__ qo, __hip_bfloat16* __restrict__ ko)
{
  const int n0 = blockIdx.x * NPB;
  const int t = threadIdx.x;
  const int w = t >> 6, l = t & 63, lg = l >> 4, lm = l & 15;
  const int h = w >> 3;      // head: 0=q 1=k
  const int c = w & 7;       // column eighth

  const __hip_bfloat16* P1 = h ? P1k : P1q;
  const __hip_bfloat16* P2 = h ? P2k : P2q;
  const float* b1  = h ? b1k  : b1q;
  const float* g1  = h ? g1k  : g1q;
  const float* be1 = h ? be1k : be1q;
  const float* b2  = h ? b2k  : b2q;
  __hip_bfloat16* out = h ? ko : qo;

  __shared__ __hip_bfloat16 As[NPB * 264];      // 16.9 KB
  __shared__ __hip_bfloat16 Hs[2][NPB * 520];   // 66.6 KB
  __shared__ float lnp[16][NPB][2];             //  4 KB
  __hip_bfloat16* Hsh = Hs[h];

  // ---- Phase 1: stream x rows, per-wave node means -> As ----
  #pragma unroll
  for (int i = 0; i < 2; ++i) {
    const int nl = w * 2 + i;
    const int node = n0 + nl;
    const int s_ = starts[node], e_ = starts[node + 1];
    f4v a0 = (f4v)0.f, a1 = (f4v)0.f, a2 = (f4v)0.f, a3 = (f4v)0.f;
    accum_rows(x, s_, e_, l, a0, a1, a2, a3);
    a0 += a1 + a2 + a3;
    const int cnt = e_ - s_;
    const float inv = cnt > 0 ? 1.0f / (float)cnt : 0.0f;
    __hip_bfloat16 o[4];
    o[0] = __float2bfloat16(a0.x * inv);
    o[1] = __float2bfloat16(a0.y * inv);
    o[2] = __float2bfloat16(a0.z * inv);
    o[3] = __float2bfloat16(a0.w * inv);
    *(uint2*)(As + nl * 264 + l * 4) = *(uint2*)o;
  }
  __syncthreads();

  // ---- Phase 2: GEMM1: C1[32][64c..] = A[32][256] x W1[256][64c..] ----
  f32x4 acc1[2][4];
  #pragma unroll
  for (int mi = 0; mi < 2; ++mi)
    #pragma unroll
    for (int nj = 0; nj < 4; ++nj)
      #pragma unroll
      for (int r = 0; r < 4; ++r) acc1[mi][nj][r] = 0.f;

  for (int ks = 0; ks < 8; ++ks) {
    short8 a0 = *(const short8*)(As + lm * 264 + ks * 32 + lg * 8);
    short8 a1 = *(const short8*)(As + (16 + lm) * 264 + ks * 32 + lg * 8);
    const __hip_bfloat16* bp = P1 + ((size_t)(ks * 32 + c * 4) * 64 + l) * 8;
    #pragma unroll
    for (int nj = 0; nj < 4; ++nj) {
      short8 b = *(const short8*)(bp + (size_t)nj * 512);
      acc1[0][nj] = MFMA16(a0, b, acc1[0][nj]);
      acc1[1][nj] = MFMA16(a1, b, acc1[1][nj]);
    }
  }

  float b1v[4], g1v[4], e1v[4];
  #pragma unroll
  for (int nj = 0; nj < 4; ++nj) {
    const int col = c * 64 + nj * 16 + lm;
    b1v[nj] = b1[col]; g1v[nj] = g1[col]; e1v[nj] = be1[col];
  }
  #pragma unroll
  for (int mi = 0; mi < 2; ++mi)
    #pragma unroll
    for (int nj = 0; nj < 4; ++nj)
      #pragma unroll
      for (int r = 0; r < 4; ++r) acc1[mi][nj][r] += b1v[nj];

  // LN partials over this wave's 64 cols (16-lane shfl reduce)
  #pragma unroll
  for (int mi = 0; mi < 2; ++mi)
    #pragma unroll
    for (int r = 0; r < 4; ++r) {
      float s = 0.f, q = 0.f;
      #pragma unroll
      for (int nj = 0; nj < 4; ++nj) {
        const float v = acc1[mi][nj][r];
        s += v; q += v * v;
      }
      #pragma unroll
      for (int off = 1; off < 16; off <<= 1) {
        s += __shfl_xor(s, off);
        q += __shfl_xor(q, off);
      }
      if (lm == 0) {
        const int row = mi * 16 + lg * 4 + r;
        lnp[w][row][0] = s;
        lnp[w][row][1] = q;
      }
    }
  __syncthreads();

  // ---- Phase 3: finish LN (combine this head's 8 waves), relu -> Hs[h] ----
  #pragma unroll
  for (int mi = 0; mi < 2; ++mi)
    #pragma unroll
    for (int r = 0; r < 4; ++r) {
      const int row = mi * 16 + lg * 4 + r;
      float S = 0.f, Q = 0.f;
      #pragma unroll
      for (int w2 = 0; w2 < 8; ++w2) {
        S += lnp[h * 8 + w2][row][0];
        Q += lnp[h * 8 + w2][row][1];
      }
      const float mu = S * (1.0f / HID);
      const float rs = rsqrtf(Q * (1.0f / HID) - mu * mu + EPSV);
      #pragma unroll
      for (int nj = 0; nj < 4; ++nj) {
        const float y = (acc1[mi][nj][r] - mu) * rs * g1v[nj] + e1v[nj];
        Hsh[row * 520 + c * 64 + nj * 16 + lm] = __float2bfloat16(fmaxf(y, 0.f));
      }
    }
  __syncthreads();

  // ---- Phase 4: GEMM2: C2[32][32c..] = h[32][512] x W2[512][32c..] ----
  f32x4 acc2[2][2];
  #pragma unroll
  for (int mi = 0; mi < 2; ++mi)
    #pragma unroll
    for (int nj = 0; nj < 2; ++nj)
      #pragma unroll
      for (int r = 0; r < 4; ++r) acc2[mi][nj][r] = 0.f;

  for (int ks = 0; ks < 16; ++ks) {
    short8 a0 = *(const short8*)(Hsh + lm * 520 + ks * 32 + lg * 8);
    short8 a1 = *(const short8*)(Hsh + (16 + lm) * 520 + ks * 32 + lg * 8);
    const __hip_bfloat16* bp = P2 + ((size_t)(ks * 16 + c * 2) * 64 + l) * 8;
    #pragma unroll
    for (int nj = 0; nj < 2; ++nj) {
      short8 b = *(const short8*)(bp + (size_t)nj * 512);
      acc2[0][nj] = MFMA16(a0, b, acc2[0][nj]);
      acc2[1][nj] = MFMA16(a1, b, acc2[1][nj]);
    }
  }

  float b2v[2];
  #pragma unroll
  for (int nj = 0; nj < 2; ++nj) b2v[nj] = b2[c * 32 + nj * 16 + lm];
  #pragma unroll
  for (int mi = 0; mi < 2; ++mi)
    #pragma unroll
    for (int nj = 0; nj < 2; ++nj)
      #pragma unroll
      for (int r = 0; r < 4; ++r) {
        const int row = n0 + mi * 16 + lg * 4 + r;
        const int col = c * 32 + nj * 16 + lm;
        out[(size_t)row * OUT_C + col] = __float2bfloat16(acc2[mi][nj][r] + b2v[nj]);
      }
}

// ---------------------------------------------------------------------------
// Kernel 2: out[b] = q_b @ k_b^T, fp32 out. 64x64 tile, 1024 blocks of 4
// waves -> 4 blocks/CU, 4 waves/SIMD. Wave w computes rows [16w,16w+16).
// Operands are contiguous 16 B fragments from L2-resident q/k (no LDS).
// ---------------------------------------------------------------------------
__global__ __launch_bounds__(256, 4) void bmm_k(
    const __hip_bfloat16* __restrict__ q, const __hip_bfloat16* __restrict__ k,
    float* __restrict__ out)
{
  const int b  = blockIdx.z;
  const int n0 = blockIdx.x * 64;
  const int m0 = blockIdx.y * 64;
  const int t = threadIdx.x;
  const int w = t >> 6, l = t & 63, lg = l >> 4, lm = l & 15;

  const __hip_bfloat16* qb = q + ((size_t)b * MAXN + n0 + w * 16) * OUT_C;
  const __hip_bfloat16* kb = k + ((size_t)b * MAXN + m0) * OUT_C;

  f32x4 acc[4];
  #pragma unroll
  for (int nj = 0; nj < 4; ++nj)
    #pragma unroll
    for (int r = 0; r < 4; ++r) acc[nj][r] = 0.f;

  for (int ks = 0; ks < 8; ++ks) {
    short8 a = *(const short8*)(qb + (size_t)lm * OUT_C + ks * 32 + lg * 8);
    #pragma unroll
    for (int nj = 0; nj < 4; ++nj) {
      short8 bb = *(const short8*)(kb + (size_t)(nj * 16 + lm) * OUT_C + ks * 32 + lg * 8);
      acc[nj] = MFMA16(a, bb, acc[nj]);
    }
  }

  #pragma unroll
  for (int nj = 0; nj < 4; ++nj)
    #pragma unroll
    for (int r = 0; r < 4; ++r) {
      const int nrow = n0 + w * 16 + lg * 4 + r;   // q node (output row)
      const int mcol = m0 + nj * 16 + lm;          // k node (output col)
      out[((size_t)b * MAXN + nrow) * MAXN + mcol] = acc[nj][r];
    }
}

// ---------------------------------------------------------------------------
extern "C" void kernel_launch(void* const* d_in, const int* in_sizes, int n_in,
                              void* d_out, int out_size, void* d_ws, size_t ws_size,
                              hipStream_t stream)
{
  const float* x   = (const float*)d_in[0];
  const int*   fpb = (const int*)d_in[1];
  // d_in[2]=g_node_batches (repeat(arange(16),512) -> pad/split is identity
  // reshape), d_in[3]=num_graphs, d_in[4]=max_nodes.
  const float* Wq_w1  = (const float*)d_in[5];
  const float* Wq_b1  = (const float*)d_in[6];
  const float* Wq_g1  = (const float*)d_in[7];
  const float* Wq_be1 = (const float*)d_in[8];
  const float* Wq_w2  = (const float*)d_in[9];
  const float* Wq_b2  = (const float*)d_in[10];
  const float* Wk_w1  = (const float*)d_in[11];
  const float* Wk_b1  = (const float*)d_in[12];
  const float* Wk_g1  = (const float*)d_in[13];
  const float* Wk_be1 = (const float*)d_in[14];
  const float* Wk_w2  = (const float*)d_in[15];
  const float* Wk_b2  = (const float*)d_in[16];

  __hip_bfloat16* ws = (__hip_bfloat16*)d_ws;
  __hip_bfloat16* P1q  = ws;                 // 131072 bf16 each
  __hip_bfloat16* P1k  = P1q + 131072;
  __hip_bfloat16* P2q  = P1k + 131072;
  __hip_bfloat16* P2k  = P2q + 131072;
  __hip_bfloat16* qo   = P2k + 131072;       // 8192*256
  __hip_bfloat16* ko   = qo + 2097152;
  int* starts = (int*)(ko + 2097152);        // 8193 ints
  float* out = (float*)d_out;

  prelude_k<<<1280, 256, 0, stream>>>(fpb, starts,
      Wq_w1, Wk_w1, Wq_w2, Wk_w2, P1q, P1k, P2q, P2k);
  fused_mlp_k<<<N_NODES / NPB, 1024, 0, stream>>>(
      x, starts, P1q, P2q, Wq_b1, Wq_g1, Wq_be1, Wq_b2,
      P1k, P2k, Wk_b1, Wk_g1, Wk_be1, Wk_b2, qo, ko);
  bmm_k<<<dim3(8, 8, NB), 256, 0, stream>>>(qo, ko, out);
}